// Round 4
// baseline (180.135 us; speedup 1.0000x reference)
//
#include <hip/hip_runtime.h>

typedef unsigned short u16;
typedef __attribute__((ext_vector_type(8))) __bf16 bf16x8;
typedef __attribute__((ext_vector_type(4))) float f32x4;
typedef __attribute__((ext_vector_type(4))) u16 u16x4;

// ---------------- helpers ----------------

__device__ __forceinline__ u16 f2bf(float f) {
  unsigned u = __float_as_uint(f);
  u += 0x7fff + ((u >> 16) & 1);   // RNE
  return (u16)(u >> 16);
}

__device__ __forceinline__ f32x4 mfma16(bf16x8 a, bf16x8 b, f32x4 c) {
  return __builtin_amdgcn_mfma_f32_16x16x32_bf16(a, b, c, 0, 0, 0);
}

__device__ __forceinline__ void gload16(const void* g, void* l) {
  __builtin_amdgcn_global_load_lds(
      (__attribute__((address_space(1))) unsigned int*)(const_cast<void*>(g)),
      (__attribute__((address_space(3))) unsigned int*)l, 16, 0, 0);
}

// ---------------- prep kernels (fused) ----------------

__global__ void k_f32_to_bf16(const float* __restrict__ in, u16* __restrict__ out, int n4) {
  int i = blockIdx.x * blockDim.x + threadIdx.x;
  if (i < n4) {
    float4 v = reinterpret_cast<const float4*>(in)[i];
    u16x4 o;
    o.x = f2bf(v.x); o.y = f2bf(v.y); o.z = f2bf(v.z); o.w = f2bf(v.w);
    reinterpret_cast<u16x4*>(out)[i] = o;
  }
}

// rel f32->bf16 (blocks 0..63) + bias pack (blocks 64..75) in one launch
__global__ void k_prep_small(const float* __restrict__ rel, u16* __restrict__ relb,
                             const float* __restrict__ bq, const float* __restrict__ bk,
                             const float* __restrict__ bv, float* __restrict__ bias) {
  const int bx = blockIdx.x, t = threadIdx.x;
  if (bx < 64) {
    int i = bx * 256 + t;          // 16384 float4 chunks
    float4 v = reinterpret_cast<const float4*>(rel)[i];
    u16x4 o;
    o.x = f2bf(v.x); o.y = f2bf(v.y); o.z = f2bf(v.z); o.w = f2bf(v.w);
    reinterpret_cast<u16x4*>(relb)[i] = o;
  } else {
    int i = (bx - 64) * 256 + t;
    if (i < 3072) bias[i] = (i < 1024) ? bq[i] : (i < 2048 ? bk[i - 1024] : bv[i - 2048]);
  }
}

// Wt[n][k] = W[k][n], fp32 -> bf16, all four weights in one launch (grid.z = 4)
__global__ void k_transpose_w4(const float* __restrict__ W0, const float* __restrict__ W1,
                               const float* __restrict__ W2, const float* __restrict__ W3,
                               u16* __restrict__ outbase) {
  __shared__ float tile[32][33];
  const int z = blockIdx.z;
  const float* in = (z == 0) ? W0 : (z == 1) ? W1 : (z == 2) ? W2 : W3;
  u16* out = outbase + (size_t)z * 1024 * 1024;
  const int r0 = blockIdx.y * 32, c0 = blockIdx.x * 32;
  const int t = threadIdx.x;
  for (int i = t; i < 1024; i += 256) {
    int r = i >> 5, c = i & 31;
    tile[r][c] = in[(size_t)(r0 + r) * 1024 + c0 + c];
  }
  __syncthreads();
  for (int i = t; i < 1024; i += 256) {
    int r = i >> 5, c = i & 31;
    out[(size_t)(c0 + r) * 1024 + r0 + c] = f2bf(tile[c][r]);
  }
}

// ---------------- GEMM: C[m][n] = sum_k A[m][k]*B[n][k] + bias[n] ----------------
// MODE 0: fp32 output. MODE 2: bf16 output, and cols >= 2048 (the V block of the
// fused QKV GEMM) are routed to Vaux in transposed layout
// Vaux[(b*1024 + (col-2048))*1024 + s], replacing the separate transpose kernel.

template<int MODE>
__global__ __launch_bounds__(256) void k_gemm(
    const u16* __restrict__ A, const u16* __restrict__ B,
    const float* __restrict__ bias, void* __restrict__ Cout,
    u16* __restrict__ Vaux, int M, int N, int Kd)
{
  __shared__ u16 Alds[128 * 32];
  __shared__ u16 Blds[128 * 32];
  const int t = threadIdx.x;
  const int lane = t & 63, wid = t >> 6;
  const int wr = wid >> 1, wc = wid & 1;
  const int l15 = lane & 15, lg = lane >> 4;
  const int m0 = blockIdx.y * 128, n0 = blockIdx.x * 128;
  const int trow = t >> 2;
  const int tcol = (t & 3) * 8;

  const f32x4 fzero = {0.f, 0.f, 0.f, 0.f};
  f32x4 acc[4][4];
#pragma unroll
  for (int i = 0; i < 4; i++)
#pragma unroll
    for (int j = 0; j < 4; j++) acc[i][j] = fzero;

  const size_t aoff0 = (size_t)(m0 + trow) * Kd + tcol;
  const size_t aoff1 = (size_t)(m0 + 64 + trow) * Kd + tcol;
  const size_t boff0 = (size_t)(n0 + trow) * Kd + tcol;
  const size_t boff1 = (size_t)(n0 + 64 + trow) * Kd + tcol;
  u16* la0 = Alds + wid * 512;
  u16* la1 = Alds + 2048 + wid * 512;
  u16* lb0 = Blds + wid * 512;
  u16* lb1 = Blds + 2048 + wid * 512;

  for (int k0 = 0; k0 < Kd; k0 += 32) {
    gload16(A + aoff0 + k0, la0);
    gload16(A + aoff1 + k0, la1);
    gload16(B + boff0 + k0, lb0);
    gload16(B + boff1 + k0, lb1);
    __syncthreads();
    bf16x8 av[4], bv[4];
#pragma unroll
    for (int mi = 0; mi < 4; mi++)
      av[mi] = *reinterpret_cast<const bf16x8*>(Alds + (wr * 64 + mi * 16 + l15) * 32 + lg * 8);
#pragma unroll
    for (int ni = 0; ni < 4; ni++)
      bv[ni] = *reinterpret_cast<const bf16x8*>(Blds + (wc * 64 + ni * 16 + l15) * 32 + lg * 8);
#pragma unroll
    for (int mi = 0; mi < 4; mi++)
#pragma unroll
      for (int ni = 0; ni < 4; ni++)
        acc[mi][ni] = mfma16(av[mi], bv[ni], acc[mi][ni]);
    __syncthreads();
  }

#pragma unroll
  for (int mi = 0; mi < 4; mi++) {
#pragma unroll
    for (int ni = 0; ni < 4; ni++) {
      const int col = n0 + wc * 64 + ni * 16 + l15;
      const float bcol = bias[col];
#pragma unroll
      for (int r = 0; r < 4; r++) {
        const int row = m0 + wr * 64 + mi * 16 + lg * 4 + r;
        const float v = acc[mi][ni][r] + bcol;
        if (MODE == 0) {
          ((float*)Cout)[(size_t)row * N + col] = v;
        } else {
          if (col < 2048) {
            ((u16*)Cout)[(size_t)row * N + col] = f2bf(v);
          } else {
            const int bb = row >> 10, ss = row & 1023;
            Vaux[((size_t)bb * 1024 + (col - 2048)) * 1024 + ss] = f2bf(v);
          }
        }
      }
    }
  }
}

// ---------------- attention ----------------
// v5: ALL global loads staged through LDS via global_load_lds, double-buffered.
// Per iteration: issue next tile's K/V/rel stage -> compute current tile
// entirely from LDS (zero global loads in the compute phase) -> __syncthreads
// (the only vmcnt drain, ~2k cycles after issue = latency fully hidden).
// This is the correct form of round 1's pipeline: no register global loads
// share the vmcnt queue, so no forced mid-iteration drain (round-1/2 lesson).
// rel: the 4 waves' 80-row windows overlap; union = 128 rows x 64 cols = 16 KB
// per tile, staged cooperatively (also deduplicates 4x redundant loads).
// rel combine via the round-1-VALIDATED within-group shuffle (conflict-free,
// no W LDS buffer). LDS = 2*(8+8+16)+8 = 72 KB -> 2 blocks/CU; latency hiding
// comes from the pipeline, not block TLP.

__global__ __launch_bounds__(256, 2) void k_attn(
    const u16* __restrict__ qkv,   // (4096, 3072): Q|K|V
    const u16* __restrict__ vt,    // (64*64, 1024): Vt[bh*64+d][s]
    const u16* __restrict__ relb,  // (1024, 64)
    u16* __restrict__ Oout)        // (4096, 1024)
{
  __shared__ u16 Klds[2][64 * 64];    // 2 x 8 KB, swizzled: byte = row*128 + (cb ^ ((row&7)<<4))
  __shared__ u16 Vlds[2][64 * 64];    // 2 x 8 KB, same swizzle (rows = d)
  __shared__ u16 Rlds[2][128 * 64];   // 2 x 16 KB rel panel, same swizzle
  __shared__ u16 Plds[4][16 * 64];    // 8 KB, per-wave P (bf16), swizzled rows of 128B

  const int t = threadIdx.x;
  const int lane = t & 63, w = t >> 6;
  const int l15 = lane & 15, lg = lane >> 4;
  const int blk = blockIdx.x;
  const int bh = blk & 63;             // blocks of a bh share an XCD (blk%8 == bh%8)
  // heavy-first + balanced mapping (LPT backfill over the 512 resident slots)
  const int g = blk >> 6;
  const int jq = g >> 2, rq = g & 3;
  const int qbt = (jq == 0) ? (15 - rq) : (jq == 1) ? (8 + rq) : (jq == 2) ? (7 - rq) : rq;
  const int b = bh >> 4, h = bh & 15;
  const int qb = qbt * 64;
  const int qw = qb + w * 16;

  u16* Pb = Plds[w];
  const f32x4 fzero = {0.f, 0.f, 0.f, 0.f};

  // Q A-fragments, held in registers
  const size_t qrow = (size_t)(b * 1024 + qw + l15) * 3072 + h * 64;
  bf16x8 aQ0 = *reinterpret_cast<const bf16x8*>(qkv + qrow + lg * 8);
  bf16x8 aQ1 = *reinterpret_cast<const bf16x8*>(qkv + qrow + 32 + lg * 8);

  f32x4 oacc[4];
  float l_r[4];
#pragma unroll
  for (int r = 0; r < 4; r++) { oacc[r] = fzero; l_r[r] = 0.f; }

  // K/V staging: thread t stages chunks t and t+256 (16B each); dest is linear,
  // source col inverse-swizzled so LDS holds the swizzled layout.
  const int srow = t >> 3;
  const int scb = ((t & 7) * 16) ^ ((srow & 7) << 4);
  const u16* Ks0 = qkv + (size_t)(b * 1024 + srow) * 3072 + 1024 + h * 64 + (scb >> 1);
  const u16* Ks1 = Ks0 + 32 * 3072;
  const u16* Vs0 = vt + (size_t)(bh * 64 + srow) * 1024 + (scb >> 1);
  const u16* Vs1 = Vs0 + 32 * 1024;

  // rel panel staging: 128 rows x 128 B = 1024 chunks; thread t stages chunks
  // {t, t+256, t+512, t+768}. chunk c: panel row = c>>3, col = (c&7)*16, source
  // col inverse-swizzled; global row = rstart + kt*64 + (c>>3), clamped (clamped
  // rows feed only masked entries — same argument as the original per-lane clamp).
  const int rstart = 1008 - qb - 48;   // wave w window starts at panel row 48-16w
  int rrow[4], rcol[4];
#pragma unroll
  for (int ci = 0; ci < 4; ci++) {
    const int c = t + 256 * ci;
    rrow[ci] = rstart + (c >> 3);
    rcol[ci] = ((((c & 7) * 16) ^ (((c >> 3) & 7) << 4)) >> 1);
  }

  const int nk = qbt + 1;              // uniform trip count across the 4 waves
  const float SC = 0.125f * 1.44269504f;   // fold 1/sqrt(D) and log2(e)

  // prologue: stage tile 0 into buffer 0
  gload16(Ks0, Klds[0] + t * 8);
  gload16(Ks1, Klds[0] + (t + 256) * 8);
  gload16(Vs0, Vlds[0] + t * 8);
  gload16(Vs1, Vlds[0] + (t + 256) * 8);
#pragma unroll
  for (int ci = 0; ci < 4; ci++) {
    int pr = rrow[ci];
    pr = pr < 0 ? 0 : (pr > 1023 ? 1023 : pr);
    gload16(relb + (size_t)pr * 64 + rcol[ci], Rlds[0] + (t + 256 * ci) * 8);
  }
  __syncthreads();

  int cur = 0;
  for (int kt = 0; kt < nk; kt++) {
    const int k0 = kt * 64;

    // prefetch next tile into buf[cur^1]; in flight for the whole compute phase
    if (kt + 1 < nk) {
      const int kn = k0 + 64;
      u16* kb = Klds[cur ^ 1];
      u16* vb = Vlds[cur ^ 1];
      u16* rb = Rlds[cur ^ 1];
      gload16(Ks0 + (size_t)kn * 3072, kb + t * 8);
      gload16(Ks1 + (size_t)kn * 3072, kb + (t + 256) * 8);
      gload16(Vs0 + kn, vb + t * 8);
      gload16(Vs1 + kn, vb + (t + 256) * 8);
#pragma unroll
      for (int ci = 0; ci < 4; ci++) {
        int pr = rrow[ci] + kn;
        pr = pr < 0 ? 0 : (pr > 1023 ? 1023 : pr);
        gload16(relb + (size_t)pr * 64 + rcol[ci], rb + (t + 256 * ci) * 8);
      }
    }

    // ---- compute from buf[cur]: LDS + ALU + MFMA only ----

    // content scores: 16 q x 64 k from swizzled Klds[cur]
    const char* Kb = (const char*)Klds[cur];
    f32x4 sc4[4];
#pragma unroll
    for (int tt = 0; tt < 4; tt++) sc4[tt] = fzero;
#pragma unroll
    for (int tt = 0; tt < 4; tt++) {
      const int row = tt * 16 + l15;
      const int sw = (row & 7) << 4;
      bf16x8 b0 = *reinterpret_cast<const bf16x8*>(Kb + row * 128 + ((lg * 16) ^ sw));
      bf16x8 b1 = *reinterpret_cast<const bf16x8*>(Kb + row * 128 + ((64 + lg * 16) ^ sw));
      sc4[tt] = mfma16(aQ0, b0, sc4[tt]);
      sc4[tt] = mfma16(aQ1, b1, sc4[tt]);
    }

    // rel band from the staged panel: wave w reads panel rows 48-16w .. 48-16w+79
    const char* Rb = (const char*)Rlds[cur];
    f32x4 z[5];
#pragma unroll
    for (int wj = 0; wj < 5; wj++) {
      const int pr = 48 - 16 * w + wj * 16 + l15;
      const int sw = (pr & 7) << 4;
      bf16x8 b0 = *reinterpret_cast<const bf16x8*>(Rb + pr * 128 + ((lg * 16) ^ sw));
      bf16x8 b1 = *reinterpret_cast<const bf16x8*>(Rb + pr * 128 + ((64 + lg * 16) ^ sw));
      f32x4 zz = fzero;
      zz = mfma16(aQ0, b0, zz);
      zz = mfma16(aQ1, b1, zz);
      z[wj] = zz;
    }

    // combine + mask + exp2 (defer-max: static max 0) + P write.
    // band pos needed = tt*16 + u, u = l15+15-rowi; same row as producer ->
    // within-16-group rotation (round-1 validated).
#pragma unroll
    for (int r = 0; r < 4; r++) {
      const int rowi = lg * 4 + r;
      const int q = qw + rowi;
      const int u = l15 + 15 - rowi;               // in [0,30]
      const int src = (lane & 48) | (u & 15);
      float sz[5];
#pragma unroll
      for (int wj = 0; wj < 5; wj++) sz[wj] = __shfl(z[wj][r], src);
#pragma unroll
      for (int tt = 0; tt < 4; tt++) {
        const int kg = k0 + tt * 16 + l15;
        const float wv = (u & 16) ? sz[tt + 1] : sz[tt];
        const float s = (sc4[tt][r] + wv) * SC;
        const float p = (kg <= q) ? exp2f(s) : 0.f;
        l_r[r] += p;
        const int cb = (32 * tt + 2 * l15) ^ ((rowi & 7) << 4);
        *(u16*)((char*)Pb + rowi * 128 + cb) = f2bf(p);
      }
    }
    __builtin_amdgcn_wave_barrier();
    asm volatile("" ::: "memory");     // order P writes before P reads

    // PV from swizzled Plds (A) and Vlds[cur] (B)
    const char* Vb = (const char*)Vlds[cur];
#pragma unroll
    for (int s = 0; s < 2; s++) {
      const int acb = (s * 64 + lg * 16) ^ ((l15 & 7) << 4);
      bf16x8 aP = *reinterpret_cast<const bf16x8*>((const char*)Pb + l15 * 128 + acb);
#pragma unroll
      for (int dt = 0; dt < 4; dt++) {
        const int vrow = dt * 16 + l15;
        const int vcb = (s * 64 + lg * 16) ^ ((vrow & 7) << 4);
        bf16x8 bV = *reinterpret_cast<const bf16x8*>(Vb + vrow * 128 + vcb);
        oacc[dt] = mfma16(aP, bV, oacc[dt]);
      }
    }
    __syncthreads();   // drains the prefetch (issued ~2k cycles ago) + syncs P
    cur ^= 1;
  }

  // epilogue: one row-sum reduce, scale, store
#pragma unroll
  for (int r = 0; r < 4; r++) {
    float l = l_r[r];
#pragma unroll
    for (int xm = 1; xm < 16; xm <<= 1) l += __shfl_xor(l, xm);
    const float inv = 1.f / l;
    const int q = qw + lg * 4 + r;
#pragma unroll
    for (int dt = 0; dt < 4; dt++)
      Oout[(size_t)(b * 1024 + q) * 1024 + h * 64 + dt * 16 + l15] = f2bf(oacc[dt][r] * inv);
  }
}

// ---------------- launcher ----------------

extern "C" void kernel_launch(void* const* d_in, const int* in_sizes, int n_in,
                              void* d_out, int out_size, void* d_ws, size_t ws_size,
                              hipStream_t stream) {
  const float* x   = (const float*)d_in[0];
  const float* Wq  = (const float*)d_in[1];
  const float* bq  = (const float*)d_in[2];
  const float* Wk  = (const float*)d_in[3];
  const float* bk  = (const float*)d_in[4];
  const float* Wv  = (const float*)d_in[5];
  const float* bv  = (const float*)d_in[6];
  const float* Wo  = (const float*)d_in[7];
  const float* bo  = (const float*)d_in[8];
  const float* rel = (const float*)d_in[9];

  const size_t MB = 1024 * 1024;
  char* ws = (char*)d_ws;
  u16*   xb    = (u16*)(ws);                 // 8MB; reused for attn O after QKV GEMM
  u16*   Wt    = (u16*)(ws + 8 * MB);        // 4096x1024 bf16 (Wq^T|Wk^T|Wv^T|Wo^T)
  u16*   qkvb  = (u16*)(ws + 16 * MB);       // 4096x3072 bf16 (V region unused)
  u16*   vtb   = (u16*)(ws + 40 * MB);       // 4096x1024 bf16 (transposed V)
  u16*   relbb = (u16*)(ws + 48 * MB);       // 1024x64 bf16
  float* bqkv  = (float*)(ws + 49 * MB);     // 3072 f32
  u16*   Ob    = xb;

  // 1) conversions + packs (fused)
  k_f32_to_bf16<<<4096, 256, 0, stream>>>(x, xb, 1048576);
  k_prep_small<<<76, 256, 0, stream>>>(rel, relbb, bq, bk, bv, bqkv);
  k_transpose_w4<<<dim3(32, 32, 4), 256, 0, stream>>>(Wq, Wk, Wv, Wo, Wt);

  // 2) fused QKV projection; V block written directly transposed into vtb
  k_gemm<2><<<dim3(24, 32), 256, 0, stream>>>(xb, Wt, bqkv, qkvb, vtb, 4096, 3072, 1024);

  // 3) attention (4 waves/block, 64 q-rows/block, fully LDS-staged 2-phase pipeline)
  k_attn<<<1024, 256, 0, stream>>>(qkvb, vtb, relbb, Ob);

  // 4) output projection -> fp32 d_out
  k_gemm<0><<<dim3(8, 32), 256, 0, stream>>>(Ob, Wt + 3 * MB, bo, d_out, nullptr, 4096, 1024, 1024);
}